// Round 1
// baseline (2226.460 us; speedup 1.0000x reference)
//
#include <hip/hip_runtime.h>
#include <hip/hip_bf16.h>
#include <cstddef>

#define N_NODES 16384
#define N_FEAT  16384
#define EMBED   64
#define BATCH   4096
#define N_EDGES 524288

// ---------------------------------------------------------------------------
// deg[n] = 1.0 (self-loop)
__global__ void k_deg_init(float* __restrict__ deg) {
    int n = blockIdx.x * blockDim.x + threadIdx.x;
    if (n < N_NODES) deg[n] = 1.0f;
}

// deg[dst] += 1 per edge
__global__ void k_deg_acc(const int* __restrict__ ei, float* __restrict__ deg) {
    int e = blockIdx.x * blockDim.x + threadIdx.x;
    if (e < N_EDGES) {
        int d = ei[N_EDGES + e];   // edge_index[1][e]
        atomicAdd(&deg[d], 1.0f);
    }
}

// dinv[n] = rsqrt(deg[n])   (deg >= 1 always, self-loops)
__global__ void k_dinv(float* __restrict__ deg) {
    int n = blockIdx.x * blockDim.x + threadIdx.x;
    if (n < N_NODES) deg[n] = rsqrtf(deg[n]);
}

// ---------------------------------------------------------------------------
// xw = X @ W   (M=16384, K=16384, N=64), fp32 tiled.
// Block: 256 threads, BM=64 rows, all 64 cols. Thread (tx=t&15, ty=t>>4)
// owns 4 rows x 4 cols. BK=32 K-chunk staged in LDS.
#define BM 64
#define BK 32
__global__ __launch_bounds__(256) void k_gemm(const float* __restrict__ X,
                                              const float* __restrict__ W,
                                              float* __restrict__ xw) {
    __shared__ float Xs[BM][BK + 1];  // +1 pad: row stride 33 breaks 4-way bank conflict
    __shared__ float Ws[BK][EMBED];

    const int t = threadIdx.x;
    const int tx = t & 15;        // col group: cols 4*tx .. 4*tx+3
    const int ty = t >> 4;        // row group: rows 4*ty .. 4*ty+3
    const int block_row = blockIdx.x * BM;

    float acc[4][4] = {};

    for (int k0 = 0; k0 < N_FEAT; k0 += BK) {
        // stage X chunk: 64 rows x 32 k = 512 float4, 2 per thread
        #pragma unroll
        for (int i = 0; i < 2; i++) {
            int f = t + i * 256;          // 0..511
            int row = f >> 3;             // 8 float4 per row
            int kq  = f & 7;
            float4 v = *(const float4*)(X + (size_t)(block_row + row) * N_FEAT + k0 + kq * 4);
            Xs[row][kq * 4 + 0] = v.x;
            Xs[row][kq * 4 + 1] = v.y;
            Xs[row][kq * 4 + 2] = v.z;
            Xs[row][kq * 4 + 3] = v.w;
        }
        // stage W chunk: 32 k x 64 cols = 512 float4, 2 per thread
        #pragma unroll
        for (int i = 0; i < 2; i++) {
            int f = t + i * 256;
            int kr = f >> 4;              // 16 float4 per k-row
            int cq = f & 15;
            float4 v = *(const float4*)(W + (size_t)(k0 + kr) * EMBED + cq * 4);
            *(float4*)(&Ws[kr][cq * 4]) = v;
        }
        __syncthreads();

        #pragma unroll
        for (int kk = 0; kk < BK; kk++) {
            float4 wv = *(const float4*)(&Ws[kk][tx * 4]);
            float xr[4];
            #pragma unroll
            for (int r = 0; r < 4; r++) xr[r] = Xs[ty * 4 + r][kk];
            #pragma unroll
            for (int r = 0; r < 4; r++) {
                acc[r][0] += xr[r] * wv.x;
                acc[r][1] += xr[r] * wv.y;
                acc[r][2] += xr[r] * wv.z;
                acc[r][3] += xr[r] * wv.w;
            }
        }
        __syncthreads();
    }

    #pragma unroll
    for (int r = 0; r < 4; r++) {
        int row = block_row + ty * 4 + r;
        float4 v = make_float4(acc[r][0], acc[r][1], acc[r][2], acc[r][3]);
        *(float4*)(xw + (size_t)row * EMBED + tx * 4) = v;
    }
}

// ---------------------------------------------------------------------------
// agg[n][d] = xw[n][d] * dinv[n]^2   (self-loop term; also initializes agg)
__global__ void k_selfloop(const float* __restrict__ xw, const float* __restrict__ dinv,
                           float* __restrict__ agg) {
    unsigned idx = blockIdx.x * blockDim.x + threadIdx.x;  // N_NODES*64 = 1M
    int n = idx >> 6;
    float di = dinv[n];
    agg[idx] = xw[idx] * di * di;
}

// agg[dst][d] += xw[src][d] * dinv[src] * dinv[dst]  — one lane per (edge, dim)
__global__ void k_edges(const int* __restrict__ ei, const float* __restrict__ xw,
                        const float* __restrict__ dinv, float* __restrict__ agg) {
    unsigned idx = blockIdx.x * blockDim.x + threadIdx.x;  // E*64 = 33.5M
    unsigned e = idx >> 6;
    unsigned d = idx & 63;
    int s = ei[e];             // edge_index[0][e]
    int t = ei[N_EDGES + e];   // edge_index[1][e]
    float norm = dinv[s] * dinv[t];
    atomicAdd(&agg[(size_t)t * EMBED + d], xw[(size_t)s * EMBED + d] * norm);
}

// ---------------------------------------------------------------------------
// out[b] = w_lin[i0] + w_lin[i1] + b_lin + dot(emb[i0]+b_gcn, emb[i1]+b_gcn)
// one wave (64 lanes) per batch row
__global__ void k_final(const int* __restrict__ x, const float* __restrict__ agg,
                        const float* __restrict__ b_gcn, const float* __restrict__ w_lin,
                        const float* __restrict__ b_lin, float* __restrict__ out) {
    int b = blockIdx.x * (blockDim.x >> 6) + (threadIdx.x >> 6);
    int lane = threadIdx.x & 63;
    if (b >= BATCH) return;
    int i0 = x[2 * b + 0];
    int i1 = x[2 * b + 1];
    float bg = b_gcn[lane];
    float e0 = agg[(size_t)i0 * EMBED + lane] + bg;
    float e1 = agg[(size_t)i1 * EMBED + lane] + bg;
    float p = e0 * e1;
    #pragma unroll
    for (int off = 32; off > 0; off >>= 1) p += __shfl_down(p, off, 64);
    if (lane == 0) out[b] = p + w_lin[i0] + w_lin[i1] + b_lin[0];
}

// ---------------------------------------------------------------------------
extern "C" void kernel_launch(void* const* d_in, const int* in_sizes, int n_in,
                              void* d_out, int out_size, void* d_ws, size_t ws_size,
                              hipStream_t stream) {
    (void)in_sizes; (void)n_in; (void)out_size; (void)ws_size;

    const int*   x   = (const int*)d_in[0];    // [BATCH, 2]
    const float* X   = (const float*)d_in[1];  // [N_NODES, N_FEAT]
    const int*   ei  = (const int*)d_in[2];    // [2, N_EDGES]
    const float* W   = (const float*)d_in[3];  // [N_FEAT, EMBED]
    const float* bg  = (const float*)d_in[4];  // [EMBED]
    const float* wl  = (const float*)d_in[5];  // [N_NODES]
    const float* bl  = (const float*)d_in[6];  // [1]
    float* out = (float*)d_out;                // [BATCH]

    char* ws = (char*)d_ws;
    float* xw   = (float*)(ws);                          // 16384*64*4 = 4 MB
    float* agg  = (float*)(ws + (size_t)(4 << 20));      // 4 MB
    float* dinv = (float*)(ws + (size_t)(8 << 20));      // 64 KB

    k_deg_init<<<N_NODES / 256, 256, 0, stream>>>(dinv);
    k_deg_acc<<<N_EDGES / 256, 256, 0, stream>>>(ei, dinv);
    k_dinv<<<N_NODES / 256, 256, 0, stream>>>(dinv);

    k_gemm<<<N_NODES / BM, 256, 0, stream>>>(X, W, xw);

    k_selfloop<<<(N_NODES * EMBED) / 256, 256, 0, stream>>>(xw, dinv, agg);
    k_edges<<<(N_EDGES * EMBED) / 256, 256, 0, stream>>>(ei, xw, dinv, agg);

    k_final<<<BATCH / 4, 256, 0, stream>>>(x, agg, bg, wl, bl, out);
}